// Round 8
// baseline (397.960 us; speedup 1.0000x reference)
//
#include <hip/hip_runtime.h>
#include <hip/hip_bf16.h>

#define NN 4096
#define IN_F 256
#define OUT_F 128
#define ALPHA 0.2f

typedef __bf16 bf16x8 __attribute__((ext_vector_type(8)));
typedef float f32x4 __attribute__((ext_vector_type(4)));
typedef float f32x16 __attribute__((ext_vector_type(16)));

__device__ __forceinline__ unsigned short f2bf(float f) {
  union { float f; unsigned int u; } x; x.f = f;
  unsigned int r = x.u + 0x7FFF + ((x.u >> 16) & 1);
  return (unsigned short)(r >> 16);
}

// ---- Wtb[i][c][k] = bf16(W[i*256+k][c]) ----
__global__ __launch_bounds__(256) void k_cvt_w(const float* __restrict__ W,
                                               unsigned short* __restrict__ Wtb) {
  const int i = blockIdx.y;
  const int k0 = blockIdx.x * 32;
  const int t = threadIdx.x;
  __shared__ float tile[32][129];
  #pragma unroll
  for (int j = 0; j < 16; ++j) {
    int idx = t + j * 256;
    int r = idx >> 7, c = idx & 127;
    tile[r][c] = W[(size_t)(i * IN_F + k0 + r) * OUT_F + c];
  }
  __syncthreads();
  const int c = t >> 1, half = t & 1;
  unsigned short* dst = Wtb + ((size_t)i * OUT_F + c) * IN_F + k0 + half * 16;
  #pragma unroll
  for (int g = 0; g < 4; ++g) {
    ushort4 v;
    v.x = f2bf(tile[half * 16 + g * 4 + 0][c]);
    v.y = f2bf(tile[half * 16 + g * 4 + 1][c]);
    v.z = f2bf(tile[half * 16 + g * 4 + 2][c]);
    v.w = f2bf(tile[half * 16 + g * 4 + 3][c]);
    *(ushort4*)(dst + g * 4) = v;
  }
}

// ---- K1 mega: Whnew_i = h@W_i (MFMA) -> Wh1/Wh2, ew2 (exp), gmax (atomicMax),
// Vopt fragment-order bf16 tiles, Whnew2 (i==2 only). grid (128,3), block 256. ----
__global__ __launch_bounds__(256) void k_front(const float* __restrict__ h,
                                               const unsigned short* __restrict__ Wtb,
                                               const float* __restrict__ a,
                                               float* __restrict__ Whnew2,
                                               unsigned short* __restrict__ Vopt,
                                               float* __restrict__ Wh1,
                                               float* __restrict__ Wh2,
                                               unsigned short* __restrict__ ew2pb,
                                               unsigned short* __restrict__ ew2mb,
                                               float* __restrict__ gmax2) {
  const int i = blockIdx.y;
  const int r0 = blockIdx.x * 32;
  const int t = threadIdx.x;
  const int lane = t & 63, wid = t >> 6;
  const int m = wid & 1, nh = wid >> 1, nbase = nh * 64;
  const int ln = lane & 15, lk = lane >> 4;

  __shared__ float a1s[128], a2s[128];
  __shared__ float red1[2][32], red2[2][32];
  __shared__ float ewsp[32], ewsm[32];
  __shared__ unsigned short T[2][32][130];

  if (t < 128) {
    a1s[t] = a[(size_t)2 * i * OUT_F + t];
    a2s[t] = a[(size_t)(2 * i + 1) * OUT_F + t];
  }
  __syncthreads();

  const float* ap = h + (size_t)(r0 + m * 16 + ln) * IN_F + lk * 8;
  const unsigned short* bp = Wtb + ((size_t)i * OUT_F + nbase + ln) * IN_F + lk * 8;

  f32x4 z4 = {0.f, 0.f, 0.f, 0.f};
  f32x4 acc[4] = {z4, z4, z4, z4};
  #pragma unroll
  for (int ks = 0; ks < 8; ++ks) {
    float4 h0 = *(const float4*)(ap + ks * 32);
    float4 h1 = *(const float4*)(ap + ks * 32 + 4);
    union { unsigned short u[8]; bf16x8 v; } av;
    av.u[0] = f2bf(h0.x); av.u[1] = f2bf(h0.y); av.u[2] = f2bf(h0.z); av.u[3] = f2bf(h0.w);
    av.u[4] = f2bf(h1.x); av.u[5] = f2bf(h1.y); av.u[6] = f2bf(h1.z); av.u[7] = f2bf(h1.w);
    acc[0] = __builtin_amdgcn_mfma_f32_16x16x32_bf16(av.v, *(const bf16x8*)(bp + 0 * 16 * IN_F + ks * 32), acc[0], 0, 0, 0);
    acc[1] = __builtin_amdgcn_mfma_f32_16x16x32_bf16(av.v, *(const bf16x8*)(bp + 1 * 16 * IN_F + ks * 32), acc[1], 0, 0, 0);
    acc[2] = __builtin_amdgcn_mfma_f32_16x16x32_bf16(av.v, *(const bf16x8*)(bp + 2 * 16 * IN_F + ks * 32), acc[2], 0, 0, 0);
    acc[3] = __builtin_amdgcn_mfma_f32_16x16x32_bf16(av.v, *(const bf16x8*)(bp + 3 * 16 * IN_F + ks * 32), acc[3], 0, 0, 0);
  }

  float d1[4] = {0.f, 0.f, 0.f, 0.f}, d2[4] = {0.f, 0.f, 0.f, 0.f};
  #pragma unroll
  for (int f = 0; f < 4; ++f) {
    const int col = nbase + f * 16 + ln;
    const float va1 = a1s[col], va2 = a2s[col];
    #pragma unroll
    for (int q = 0; q < 4; ++q) {
      const float v = acc[f][q];
      d1[q] += v * va1;
      d2[q] += v * va2;
    }
  }
  #pragma unroll
  for (int msk = 1; msk < 16; msk <<= 1) {
    #pragma unroll
    for (int q = 0; q < 4; ++q) {
      d1[q] += __shfl_xor(d1[q], msk, 64);
      d2[q] += __shfl_xor(d2[q], msk, 64);
    }
  }
  if (ln == 0) {
    #pragma unroll
    for (int q = 0; q < 4; ++q) {
      red1[nh][m * 16 + lk * 4 + q] = d1[q];
      red2[nh][m * 16 + lk * 4 + q] = d2[q];
    }
  }
  if (i == 2) {
    #pragma unroll
    for (int f = 0; f < 4; ++f) {
      const int col = nbase + f * 16 + ln;
      #pragma unroll
      for (int q = 0; q < 4; ++q)
        Whnew2[(size_t)(r0 + m * 16 + lk * 4 + q) * OUT_F + col] = acc[f][q];
    }
  }
  __syncthreads();

  if (t < 32) {
    const float w1 = red1[0][t] + red1[1][t];
    const float w2 = red2[0][t] + red2[1][t];
    Wh1[(size_t)i * NN + r0 + t] = w1;
    Wh2[(size_t)i * NN + r0 + t] = w2;
    const float ep = __expf(w2), em = __expf(ALPHA * w2);
    ewsp[t] = ep; ewsm[t] = em;
    ew2pb[(size_t)i * NN + r0 + t] = f2bf(ep);
    ew2mb[(size_t)i * NN + r0 + t] = f2bf(em);
    float mv = w2;
    #pragma unroll
    for (int o = 16; o > 0; o >>= 1) mv = fmaxf(mv, __shfl_down(mv, o, 32));
    if (t == 0 && mv > 0.f)
      atomicMax((int*)gmax2 + i, __float_as_int(mv));
  }
  __syncthreads();

  // scatter e~*v products into transpose tile (c-major -> n-major)
  #pragma unroll
  for (int f = 0; f < 4; ++f) {
    const int n = nbase + f * 16 + ln;
    #pragma unroll
    for (int q = 0; q < 4; ++q) {
      const int c = m * 16 + lk * 4 + q;
      const float v = acc[f][q];
      T[0][c][n] = f2bf(ewsp[c] * v);
      T[1][c][n] = f2bf(ewsm[c] * v);
    }
  }
  __syncthreads();

  // coalesced fragment-order write: Vopt[(i*2+s)*256 + kslab][n][cl]
  const int n = t & 127, ks = t >> 7;
  const int kslab = (r0 >> 4) + ks;
  #pragma unroll
  for (int s = 0; s < 2; ++s) {
    union { unsigned short u[16]; uint4 q[2]; } o;
    #pragma unroll
    for (int j = 0; j < 16; ++j) o.u[j] = T[s][ks * 16 + j][n];
    unsigned short* dst = Vopt + (((size_t)(i * 2 + s) * 256 + kslab) * 128 + n) * 16;
    *(uint4*)(dst) = o.q[0];
    *(uint4*)(dst + 8) = o.q[1];
  }
}

// ---- K_heavy: fused mask->fragments->MFMA. Reads mask ONCE, no Bits buffer,
// no LDS, no barriers, no atomics. grid (64,3,4), XCD-swizzled. ----
__global__ __launch_bounds__(256) void k_heavy(const unsigned short* __restrict__ Vopt,
                                               const int* __restrict__ mask,
                                               const float* __restrict__ Wh1,
                                               const float* __restrict__ Wh2,
                                               const unsigned short* __restrict__ ew2pb,
                                               const unsigned short* __restrict__ ew2mb,
                                               const float* __restrict__ gmax2,
                                               float* __restrict__ Upart,
                                               float* __restrict__ SPp,
                                               float* __restrict__ SMp) {
  // bijective XCD swizzle: 768 blocks, 96 consecutive work-items per XCD
  const unsigned int lid = blockIdx.x + 64u * (blockIdx.y + 3u * blockIdx.z);
  const unsigned int swz = (lid & 7u) * 96u + (lid >> 3);
  const int bx = swz & 63;
  const int w = swz >> 6;
  const int i = w % 3;
  const int z = w / 3;

  const int r0 = bx * 64;
  const int cb = z * 1024;
  const int t = threadIdx.x, lane = t & 63, wid = t >> 6;
  const int m = wid & 1, nh = wid >> 1;
  const int l31 = lane & 31, kh = lane >> 5;
  const int n0 = nh * 64 + l31, n1 = n0 + 32;

  const int myrow = r0 + m * 32 + l31;
  const float w1 = Wh1[(size_t)i * NN + myrow];
  const int* mrow = mask + ((size_t)i * NN + myrow) * NN + cb + kh * 8;
  const float* w2p = Wh2 + (size_t)i * NN + cb + kh * 8;

  const size_t fragoff = (size_t)nh * 1024 + l31 * 16 + kh * 8;
  const unsigned short* vP = Vopt + ((size_t)(i * 2 + 0) * 256 + (cb >> 4)) * 2048 + fragoff;
  const unsigned short* vM = Vopt + ((size_t)(i * 2 + 1) * 256 + (cb >> 4)) * 2048 + fragoff;
  const unsigned short* eB = (nh == 0 ? ew2pb : ew2mb) + (size_t)i * NN + cb + kh * 8;

  f32x16 accP0 = {}, accP1 = {}, accM0 = {}, accM1 = {}, accS = {};

  #pragma unroll 2
  for (int kslab = 0; kslab < 64; ++kslab) {
    const int ks16 = kslab * 16;
    int4 ma = *(const int4*)(mrow + ks16);
    int4 mb = *(const int4*)(mrow + ks16 + 4);
    float4 wa = *(const float4*)(w2p + ks16);
    float4 wb = *(const float4*)(w2p + ks16 + 4);

    union { unsigned int u[4]; bf16x8 v; } aP, aM;
    {
      int mv[8] = {ma.x, ma.y, ma.z, ma.w, mb.x, mb.y, mb.z, mb.w};
      float wv[8] = {wa.x, wa.y, wa.z, wa.w, wb.x, wb.y, wb.z, wb.w};
      #pragma unroll
      for (int e = 0; e < 4; ++e) {
        const bool m0 = mv[2 * e] > 0,   p0 = (w1 + wv[2 * e]) > 0.f;
        const bool m1 = mv[2 * e + 1] > 0, p1 = (w1 + wv[2 * e + 1]) > 0.f;
        aP.u[e] = ((m0 && p0) ? 0x3F80u : 0u) | ((m1 && p1) ? 0x3F800000u : 0u);
        aM.u[e] = ((m0 && !p0) ? 0x3F80u : 0u) | ((m1 && !p1) ? 0x3F800000u : 0u);
      }
    }
    bf16x8 bP0 = *(const bf16x8*)(vP + (size_t)kslab * 2048);
    bf16x8 bP1 = *(const bf16x8*)(vP + (size_t)kslab * 2048 + 512);
    bf16x8 bM0 = *(const bf16x8*)(vM + (size_t)kslab * 2048);
    bf16x8 bM1 = *(const bf16x8*)(vM + (size_t)kslab * 2048 + 512);
    bf16x8 eF  = *(const bf16x8*)(eB + ks16);
    accP0 = __builtin_amdgcn_mfma_f32_32x32x16_bf16(aP.v, bP0, accP0, 0, 0, 0);
    accP1 = __builtin_amdgcn_mfma_f32_32x32x16_bf16(aP.v, bP1, accP1, 0, 0, 0);
    accM0 = __builtin_amdgcn_mfma_f32_32x32x16_bf16(aM.v, bM0, accM0, 0, 0, 0);
    accM1 = __builtin_amdgcn_mfma_f32_32x32x16_bf16(aM.v, bM1, accM1, 0, 0, 0);
    accS  = __builtin_amdgcn_mfma_f32_32x32x16_bf16(nh == 0 ? aP.v : aM.v, eF, accS, 0, 0, 0);
  }

  const float gi = gmax2[i];
  const int rbase = r0 + m * 32;
  #pragma unroll
  for (int q = 0; q < 16; ++q) {
    const int crow = (q & 3) + 8 * (q >> 2) + 4 * kh;
    const int r = rbase + crow;
    const float rw1 = Wh1[(size_t)i * NN + r];
    const float e0 = rw1 + gi;
    const float mx = (e0 > 0.f) ? e0 : ALPHA * e0;
    const float fp = __expf(rw1 - mx);
    const float fm = __expf(ALPHA * rw1 - mx);
    float* urow = Upart + ((size_t)(z * 3 + i) * NN + r) * OUT_F;
    urow[n0] = fp * accP0[q] + fm * accM0[q];
    urow[n1] = fp * accP1[q] + fm * accM1[q];
  }
  if (l31 == 0) {
    #pragma unroll
    for (int q = 0; q < 16; ++q) {
      const int r = rbase + (q & 3) + 8 * (q >> 2) + 4 * kh;
      if (nh == 0) SPp[(size_t)(z * 3 + i) * NN + r] = accS[q];
      else         SMp[(size_t)(z * 3 + i) * NN + r] = accS[q];
    }
  }
}

// ---- final: out = elu( sum_i coef_i*(Σz Up)/(fp ΣSP + fm ΣSM) + 0.125*Whnew2 ) ----
__global__ __launch_bounds__(256) void k_final(const float* __restrict__ Upart,
                                               const float* __restrict__ SPp,
                                               const float* __restrict__ SMp,
                                               const float* __restrict__ Wh1,
                                               const float* __restrict__ gmax2,
                                               const float* __restrict__ Whnew2,
                                               float* __restrict__ out) {
  int idx = blockIdx.x * 256 + threadIdx.x;
  int r = idx >> 7;
  float v = 0.125f * Whnew2[idx];
  #pragma unroll
  for (int i = 0; i < 3; ++i) {
    const float coef = (i == 0) ? 0.5f : (i == 1) ? 0.25f : 0.125f;
    const float w1 = Wh1[(size_t)i * NN + r];
    const float gi = gmax2[i];
    const float e0 = w1 + gi;
    const float mx = (e0 > 0.f) ? e0 : ALPHA * e0;
    const float fp = __expf(w1 - mx);
    const float fm = __expf(ALPHA * w1 - mx);
    float u = 0.f, sp = 0.f, sm = 0.f;
    #pragma unroll
    for (int zz = 0; zz < 4; ++zz) {
      u  += Upart[((size_t)(zz * 3 + i) * NN) * OUT_F + idx];
      sp += SPp[(size_t)(zz * 3 + i) * NN + r];
      sm += SMp[(size_t)(zz * 3 + i) * NN + r];
    }
    const float S = fp * sp + fm * sm;
    v += coef * u / S;
  }
  out[idx] = (v > 0.f) ? v : (__expf(v) - 1.0f);
}

extern "C" void kernel_launch(void* const* d_in, const int* in_sizes, int n_in,
                              void* d_out, int out_size, void* d_ws, size_t ws_size,
                              hipStream_t stream) {
  const float* h    = (const float*)d_in[0];
  const int*   mask = (const int*)d_in[1];
  const float* W    = (const float*)d_in[2];
  const float* a    = (const float*)d_in[3];
  float* out = (float*)d_out;

  float* Whnew2 = (float*)d_ws;                        // NN*128
  float* Wh1    = Whnew2 + (size_t)NN * OUT_F;         // 3*NN
  float* Wh2    = Wh1 + 3 * NN;                        // 3*NN
  float* gmax2  = Wh2 + 3 * NN;                        // 4
  float* Upart  = gmax2 + 4;                           // 4*3*NN*128
  float* SPp    = Upart + (size_t)4 * 3 * NN * OUT_F;  // 4*3*NN
  float* SMp    = SPp + 4 * 3 * NN;                    // 4*3*NN
  unsigned short* Wtb   = (unsigned short*)(SMp + 4 * 3 * NN);   // 3*128*256
  unsigned short* Vopt  = Wtb + (size_t)3 * OUT_F * IN_F;        // 3*2*256*128*16
  unsigned short* ew2pb = Vopt + (size_t)3 * 2 * 256 * 128 * 16; // 3*NN
  unsigned short* ew2mb = ew2pb + 3 * NN;                        // 3*NN

  hipMemsetAsync(gmax2, 0, 4 * sizeof(float), stream);  // 0 is a valid lower seed for max (upper-bound logic)
  k_cvt_w<<<dim3(8, 3), 256, 0, stream>>>(W, Wtb);
  k_front<<<dim3(128, 3), 256, 0, stream>>>(h, Wtb, a, Whnew2, Vopt, Wh1, Wh2, ew2pb, ew2mb, gmax2);
  k_heavy<<<dim3(64, 3, 4), 256, 0, stream>>>(Vopt, mask, Wh1, Wh2, ew2pb, ew2mb, gmax2, Upart, SPp, SMp);
  k_final<<<(NN * OUT_F) / 256, 256, 0, stream>>>(Upart, SPp, SMp, Wh1, gmax2, Whnew2, out);
}

// Round 9
// 396.747 us; speedup vs baseline: 1.0031x; 1.0031x over previous
//
#include <hip/hip_runtime.h>
#include <hip/hip_bf16.h>

#define NN 4096
#define IN_F 256
#define OUT_F 128
#define ALPHA 0.2f

typedef __bf16 bf16x8 __attribute__((ext_vector_type(8)));
typedef float f32x4 __attribute__((ext_vector_type(4)));
typedef float f32x16 __attribute__((ext_vector_type(16)));

__device__ __forceinline__ unsigned short f2bf(float f) {
  union { float f; unsigned int u; } x; x.f = f;
  unsigned int r = x.u + 0x7FFF + ((x.u >> 16) & 1);
  return (unsigned short)(r >> 16);
}
// 8 bits -> 8 bf16 values in {0.0, 1.0}; bit j -> element j
__device__ __forceinline__ bf16x8 bits2bf8(unsigned int b) {
  union { unsigned int u[4]; bf16x8 v; } o;
  #pragma unroll
  for (int e = 0; e < 4; ++e) {
    unsigned int lo = (b >> (2 * e)) & 1u;
    unsigned int hi = (b >> (2 * e + 1)) & 1u;
    o.u[e] = lo * 0x3F80u + hi * 0x3F800000u;
  }
  return o.v;
}

// ---- Wtb[i][c][k] = bf16(W[i*256+k][c]) ----
__global__ __launch_bounds__(256) void k_cvt_w(const float* __restrict__ W,
                                               unsigned short* __restrict__ Wtb) {
  const int i = blockIdx.y;
  const int k0 = blockIdx.x * 32;
  const int t = threadIdx.x;
  __shared__ float tile[32][129];
  #pragma unroll
  for (int j = 0; j < 16; ++j) {
    int idx = t + j * 256;
    int r = idx >> 7, c = idx & 127;
    tile[r][c] = W[(size_t)(i * IN_F + k0 + r) * OUT_F + c];
  }
  __syncthreads();
  const int c = t >> 1, half = t & 1;
  unsigned short* dst = Wtb + ((size_t)i * OUT_F + c) * IN_F + k0 + half * 16;
  #pragma unroll
  for (int g = 0; g < 4; ++g) {
    ushort4 v;
    v.x = f2bf(tile[half * 16 + g * 4 + 0][c]);
    v.y = f2bf(tile[half * 16 + g * 4 + 1][c]);
    v.z = f2bf(tile[half * 16 + g * 4 + 2][c]);
    v.w = f2bf(tile[half * 16 + g * 4 + 3][c]);
    *(ushort4*)(dst + g * 4) = v;
  }
}

// ---- K1 mega: Whnew_i = h@W_i (MFMA) -> Wh1/Wh2, ew2 (exp), gmax (atomicMax),
// Vopt fragment-order bf16 tiles, Whnew2 (i==2 only). grid (128,3), block 256. ----
__global__ __launch_bounds__(256) void k_front(const float* __restrict__ h,
                                               const unsigned short* __restrict__ Wtb,
                                               const float* __restrict__ a,
                                               float* __restrict__ Whnew2,
                                               unsigned short* __restrict__ Vopt,
                                               float* __restrict__ Wh1,
                                               float* __restrict__ Wh2,
                                               unsigned short* __restrict__ ew2pb,
                                               unsigned short* __restrict__ ew2mb,
                                               float* __restrict__ gmax2) {
  const int i = blockIdx.y;
  const int r0 = blockIdx.x * 32;
  const int t = threadIdx.x;
  const int lane = t & 63, wid = t >> 6;
  const int m = wid & 1, nh = wid >> 1, nbase = nh * 64;
  const int ln = lane & 15, lk = lane >> 4;

  __shared__ float a1s[128], a2s[128];
  __shared__ float red1[2][32], red2[2][32];
  __shared__ float ewsp[32], ewsm[32];
  __shared__ unsigned short T[2][32][130];

  if (t < 128) {
    a1s[t] = a[(size_t)2 * i * OUT_F + t];
    a2s[t] = a[(size_t)(2 * i + 1) * OUT_F + t];
  }
  __syncthreads();

  const float* ap = h + (size_t)(r0 + m * 16 + ln) * IN_F + lk * 8;
  const unsigned short* bp = Wtb + ((size_t)i * OUT_F + nbase + ln) * IN_F + lk * 8;

  f32x4 z4 = {0.f, 0.f, 0.f, 0.f};
  f32x4 acc[4] = {z4, z4, z4, z4};
  #pragma unroll
  for (int ks = 0; ks < 8; ++ks) {
    float4 h0 = *(const float4*)(ap + ks * 32);
    float4 h1 = *(const float4*)(ap + ks * 32 + 4);
    union { unsigned short u[8]; bf16x8 v; } av;
    av.u[0] = f2bf(h0.x); av.u[1] = f2bf(h0.y); av.u[2] = f2bf(h0.z); av.u[3] = f2bf(h0.w);
    av.u[4] = f2bf(h1.x); av.u[5] = f2bf(h1.y); av.u[6] = f2bf(h1.z); av.u[7] = f2bf(h1.w);
    acc[0] = __builtin_amdgcn_mfma_f32_16x16x32_bf16(av.v, *(const bf16x8*)(bp + 0 * 16 * IN_F + ks * 32), acc[0], 0, 0, 0);
    acc[1] = __builtin_amdgcn_mfma_f32_16x16x32_bf16(av.v, *(const bf16x8*)(bp + 1 * 16 * IN_F + ks * 32), acc[1], 0, 0, 0);
    acc[2] = __builtin_amdgcn_mfma_f32_16x16x32_bf16(av.v, *(const bf16x8*)(bp + 2 * 16 * IN_F + ks * 32), acc[2], 0, 0, 0);
    acc[3] = __builtin_amdgcn_mfma_f32_16x16x32_bf16(av.v, *(const bf16x8*)(bp + 3 * 16 * IN_F + ks * 32), acc[3], 0, 0, 0);
  }

  float d1[4] = {0.f, 0.f, 0.f, 0.f}, d2[4] = {0.f, 0.f, 0.f, 0.f};
  #pragma unroll
  for (int f = 0; f < 4; ++f) {
    const int col = nbase + f * 16 + ln;
    const float va1 = a1s[col], va2 = a2s[col];
    #pragma unroll
    for (int q = 0; q < 4; ++q) {
      const float v = acc[f][q];
      d1[q] += v * va1;
      d2[q] += v * va2;
    }
  }
  #pragma unroll
  for (int msk = 1; msk < 16; msk <<= 1) {
    #pragma unroll
    for (int q = 0; q < 4; ++q) {
      d1[q] += __shfl_xor(d1[q], msk, 64);
      d2[q] += __shfl_xor(d2[q], msk, 64);
    }
  }
  if (ln == 0) {
    #pragma unroll
    for (int q = 0; q < 4; ++q) {
      red1[nh][m * 16 + lk * 4 + q] = d1[q];
      red2[nh][m * 16 + lk * 4 + q] = d2[q];
    }
  }
  if (i == 2) {
    #pragma unroll
    for (int f = 0; f < 4; ++f) {
      const int col = nbase + f * 16 + ln;
      #pragma unroll
      for (int q = 0; q < 4; ++q)
        Whnew2[(size_t)(r0 + m * 16 + lk * 4 + q) * OUT_F + col] = acc[f][q];
    }
  }
  __syncthreads();

  if (t < 32) {
    const float w1 = red1[0][t] + red1[1][t];
    const float w2 = red2[0][t] + red2[1][t];
    Wh1[(size_t)i * NN + r0 + t] = w1;
    Wh2[(size_t)i * NN + r0 + t] = w2;
    const float ep = __expf(w2), em = __expf(ALPHA * w2);
    ewsp[t] = ep; ewsm[t] = em;
    ew2pb[(size_t)i * NN + r0 + t] = f2bf(ep);
    ew2mb[(size_t)i * NN + r0 + t] = f2bf(em);
    float mv = w2;
    #pragma unroll
    for (int o = 16; o > 0; o >>= 1) mv = fmaxf(mv, __shfl_down(mv, o, 32));
    if (t == 0 && mv > 0.f)
      atomicMax((int*)gmax2 + i, __float_as_int(mv));
  }
  __syncthreads();

  // scatter e~*v products into transpose tile (c-major -> n-major)
  #pragma unroll
  for (int f = 0; f < 4; ++f) {
    const int n = nbase + f * 16 + ln;
    #pragma unroll
    for (int q = 0; q < 4; ++q) {
      const int c = m * 16 + lk * 4 + q;
      const float v = acc[f][q];
      T[0][c][n] = f2bf(ewsp[c] * v);
      T[1][c][n] = f2bf(ewsm[c] * v);
    }
  }
  __syncthreads();

  // coalesced fragment-order write: Vopt[(i*2+s)*256 + kslab][n][cl]
  const int n = t & 127, ks = t >> 7;
  const int kslab = (r0 >> 4) + ks;
  #pragma unroll
  for (int s = 0; s < 2; ++s) {
    union { unsigned short u[16]; uint4 q[2]; } o;
    #pragma unroll
    for (int j = 0; j < 16; ++j) o.u[j] = T[s][ks * 16 + j][n];
    unsigned short* dst = Vopt + (((size_t)(i * 2 + s) * 256 + kslab) * 128 + n) * 16;
    *(uint4*)(dst) = o.q[0];
    *(uint4*)(dst + 8) = o.q[1];
  }
}

// ---- K_heavy: two-phase. Phase 1: coalesced mask stream -> packed bits in LDS
// (lane=col). ONE barrier. Phase 2: MFMA loop, A-bits from LDS (lane=row,
// conflict-free broadcast), V fragment-order from L2. No atomics, no Bits buffer.
// grid (64,3,4), XCD-swizzled. ----
__global__ __launch_bounds__(256) void k_heavy(const unsigned short* __restrict__ Vopt,
                                               const int* __restrict__ mask,
                                               const float* __restrict__ Wh1,
                                               const float* __restrict__ Wh2,
                                               const unsigned short* __restrict__ ew2pb,
                                               const unsigned short* __restrict__ ew2mb,
                                               const float* __restrict__ gmax2,
                                               float* __restrict__ Upart,
                                               float* __restrict__ SPp,
                                               float* __restrict__ SMp) {
  // bijective XCD swizzle: 768 blocks, 96 consecutive work-items per XCD
  const unsigned int lid = blockIdx.x + 64u * (blockIdx.y + 3u * blockIdx.z);
  const unsigned int swz = (lid & 7u) * 96u + (lid >> 3);
  const int bx = swz & 63;
  const int w = swz >> 6;
  const int i = w % 3;
  const int z = w / 3;

  const int r0 = bx * 64;
  const int cb = z * 1024;
  const int t = threadIdx.x, lane = t & 63, wid = t >> 6;
  const int m = wid & 1, nh = wid >> 1;
  const int l31 = lane & 31, kh = lane >> 5;
  const int n0 = nh * 64 + l31, n1 = n0 + 32;

  __shared__ unsigned int bitsLDS[64][65];   // [row][kslab], +1 pad word

  // ---- Phase 1: coalesced pack. wave jj-quarter = one row, lane=16-col group.
  const int wq = t >> 6;            // which of 4 rows per iteration
  const int cg = t & 63;            // 16-col group within the 1024-col window
  float w2v[16];
  {
    const float* w2b = Wh2 + (size_t)i * NN + cb + cg * 16;
    #pragma unroll
    for (int g = 0; g < 4; ++g) {
      float4 f = *(const float4*)(w2b + g * 4);
      w2v[g * 4 + 0] = f.x; w2v[g * 4 + 1] = f.y;
      w2v[g * 4 + 2] = f.z; w2v[g * 4 + 3] = f.w;
    }
  }
  const int* mcol = mask + ((size_t)i * NN + r0) * NN + cb + cg * 16;
  #pragma unroll 2
  for (int jj = 0; jj < 16; ++jj) {
    const int rl = jj * 4 + wq;
    const float w1r = Wh1[(size_t)i * NN + r0 + rl];
    const int* mp = mcol + (size_t)rl * NN;
    unsigned int bpk = 0, bmk = 0;
    #pragma unroll
    for (int g = 0; g < 4; ++g) {
      int4 mv = *(const int4*)(mp + g * 4);
      if (mv.x > 0) { if (w1r + w2v[g * 4 + 0] > 0.f) bpk |= 1u << (g * 4 + 0); else bmk |= 1u << (g * 4 + 0); }
      if (mv.y > 0) { if (w1r + w2v[g * 4 + 1] > 0.f) bpk |= 1u << (g * 4 + 1); else bmk |= 1u << (g * 4 + 1); }
      if (mv.z > 0) { if (w1r + w2v[g * 4 + 2] > 0.f) bpk |= 1u << (g * 4 + 2); else bmk |= 1u << (g * 4 + 2); }
      if (mv.w > 0) { if (w1r + w2v[g * 4 + 3] > 0.f) bpk |= 1u << (g * 4 + 3); else bmk |= 1u << (g * 4 + 3); }
    }
    bitsLDS[rl][cg] = bpk | (bmk << 16);
  }
  __syncthreads();

  // ---- Phase 2: MFMA loop (round-7 k_attn2 structure, bits from LDS)
  const size_t fragoff = (size_t)nh * 1024 + l31 * 16 + kh * 8;
  const unsigned short* vP = Vopt + ((size_t)(i * 2 + 0) * 256 + (cb >> 4)) * 2048 + fragoff;
  const unsigned short* vM = Vopt + ((size_t)(i * 2 + 1) * 256 + (cb >> 4)) * 2048 + fragoff;
  const unsigned short* eB = (nh == 0 ? ew2pb : ew2mb) + (size_t)i * NN + cb + kh * 8;
  const int arow = m * 32 + l31;

  f32x16 accP0 = {}, accP1 = {}, accM0 = {}, accM1 = {}, accS = {};

  #pragma unroll 2
  for (int ks = 0; ks < 64; ++ks) {
    const unsigned int wv = bitsLDS[arow][ks];
    bf16x8 aP = bits2bf8((wv >> (kh * 8)) & 0xFFu);
    bf16x8 aM = bits2bf8((wv >> (16 + kh * 8)) & 0xFFu);
    bf16x8 bP0 = *(const bf16x8*)(vP + (size_t)ks * 2048);
    bf16x8 bP1 = *(const bf16x8*)(vP + (size_t)ks * 2048 + 512);
    bf16x8 bM0 = *(const bf16x8*)(vM + (size_t)ks * 2048);
    bf16x8 bM1 = *(const bf16x8*)(vM + (size_t)ks * 2048 + 512);
    bf16x8 eF  = *(const bf16x8*)(eB + ks * 16);
    accP0 = __builtin_amdgcn_mfma_f32_32x32x16_bf16(aP, bP0, accP0, 0, 0, 0);
    accP1 = __builtin_amdgcn_mfma_f32_32x32x16_bf16(aP, bP1, accP1, 0, 0, 0);
    accM0 = __builtin_amdgcn_mfma_f32_32x32x16_bf16(aM, bM0, accM0, 0, 0, 0);
    accM1 = __builtin_amdgcn_mfma_f32_32x32x16_bf16(aM, bM1, accM1, 0, 0, 0);
    accS  = __builtin_amdgcn_mfma_f32_32x32x16_bf16(nh == 0 ? aP : aM, eF, accS, 0, 0, 0);
  }

  const float gi = gmax2[i];
  const int rbase = r0 + m * 32;
  #pragma unroll
  for (int q = 0; q < 16; ++q) {
    const int crow = (q & 3) + 8 * (q >> 2) + 4 * kh;
    const int r = rbase + crow;
    const float rw1 = Wh1[(size_t)i * NN + r];
    const float e0 = rw1 + gi;
    const float mx = (e0 > 0.f) ? e0 : ALPHA * e0;
    const float fp = __expf(rw1 - mx);
    const float fm = __expf(ALPHA * rw1 - mx);
    float* urow = Upart + ((size_t)(z * 3 + i) * NN + r) * OUT_F;
    urow[n0] = fp * accP0[q] + fm * accM0[q];
    urow[n1] = fp * accP1[q] + fm * accM1[q];
  }
  if (l31 == 0) {
    #pragma unroll
    for (int q = 0; q < 16; ++q) {
      const int r = rbase + (q & 3) + 8 * (q >> 2) + 4 * kh;
      if (nh == 0) SPp[(size_t)(z * 3 + i) * NN + r] = accS[q];
      else         SMp[(size_t)(z * 3 + i) * NN + r] = accS[q];
    }
  }
}

// ---- final: out = elu( sum_i coef_i*(Σz Up)/(fp ΣSP + fm ΣSM) + 0.125*Whnew2 ) ----
__global__ __launch_bounds__(256) void k_final(const float* __restrict__ Upart,
                                               const float* __restrict__ SPp,
                                               const float* __restrict__ SMp,
                                               const float* __restrict__ Wh1,
                                               const float* __restrict__ gmax2,
                                               const float* __restrict__ Whnew2,
                                               float* __restrict__ out) {
  int idx = blockIdx.x * 256 + threadIdx.x;
  int r = idx >> 7;
  float v = 0.125f * Whnew2[idx];
  #pragma unroll
  for (int i = 0; i < 3; ++i) {
    const float coef = (i == 0) ? 0.5f : (i == 1) ? 0.25f : 0.125f;
    const float w1 = Wh1[(size_t)i * NN + r];
    const float gi = gmax2[i];
    const float e0 = w1 + gi;
    const float mx = (e0 > 0.f) ? e0 : ALPHA * e0;
    const float fp = __expf(w1 - mx);
    const float fm = __expf(ALPHA * w1 - mx);
    float u = 0.f, sp = 0.f, sm = 0.f;
    #pragma unroll
    for (int zz = 0; zz < 4; ++zz) {
      u  += Upart[((size_t)(zz * 3 + i) * NN) * OUT_F + idx];
      sp += SPp[(size_t)(zz * 3 + i) * NN + r];
      sm += SMp[(size_t)(zz * 3 + i) * NN + r];
    }
    const float S = fp * sp + fm * sm;
    v += coef * u / S;
  }
  out[idx] = (v > 0.f) ? v : (__expf(v) - 1.0f);
}

extern "C" void kernel_launch(void* const* d_in, const int* in_sizes, int n_in,
                              void* d_out, int out_size, void* d_ws, size_t ws_size,
                              hipStream_t stream) {
  const float* h    = (const float*)d_in[0];
  const int*   mask = (const int*)d_in[1];
  const float* W    = (const float*)d_in[2];
  const float* a    = (const float*)d_in[3];
  float* out = (float*)d_out;

  float* Whnew2 = (float*)d_ws;                        // NN*128
  float* Wh1    = Whnew2 + (size_t)NN * OUT_F;         // 3*NN
  float* Wh2    = Wh1 + 3 * NN;                        // 3*NN
  float* gmax2  = Wh2 + 3 * NN;                        // 4
  float* Upart  = gmax2 + 4;                           // 4*3*NN*128
  float* SPp    = Upart + (size_t)4 * 3 * NN * OUT_F;  // 4*3*NN
  float* SMp    = SPp + 4 * 3 * NN;                    // 4*3*NN
  unsigned short* Wtb   = (unsigned short*)(SMp + 4 * 3 * NN);   // 3*128*256
  unsigned short* Vopt  = Wtb + (size_t)3 * OUT_F * IN_F;        // 3*2*256*128*16
  unsigned short* ew2pb = Vopt + (size_t)3 * 2 * 256 * 128 * 16; // 3*NN
  unsigned short* ew2mb = ew2pb + 3 * NN;                        // 3*NN

  hipMemsetAsync(gmax2, 0, 4 * sizeof(float), stream);  // 0 seeds atomicMax upper-bound logic
  k_cvt_w<<<dim3(8, 3), 256, 0, stream>>>(W, Wtb);
  k_front<<<dim3(128, 3), 256, 0, stream>>>(h, Wtb, a, Whnew2, Vopt, Wh1, Wh2, ew2pb, ew2mb, gmax2);
  k_heavy<<<dim3(64, 3, 4), 256, 0, stream>>>(Vopt, mask, Wh1, Wh2, ew2pb, ew2mb, gmax2, Upart, SPp, SMp);
  k_final<<<(NN * OUT_F) / 256, 256, 0, stream>>>(Upart, SPp, SMp, Wh1, gmax2, Whnew2, out);
}

// Round 10
// 346.629 us; speedup vs baseline: 1.1481x; 1.1446x over previous
//
#include <hip/hip_runtime.h>
#include <hip/hip_bf16.h>

#define NN 4096
#define IN_F 256
#define OUT_F 128
#define ALPHA 0.2f
#define ROWS 128      // rows per k_heavy block
#define WCOLS 512     // graph-cols per window (z-split = 8)

typedef __bf16 bf16x8 __attribute__((ext_vector_type(8)));
typedef float f32x4 __attribute__((ext_vector_type(4)));
typedef float f32x16 __attribute__((ext_vector_type(16)));

__device__ __forceinline__ unsigned short f2bf(float f) {
  union { float f; unsigned int u; } x; x.f = f;
  unsigned int r = x.u + 0x7FFF + ((x.u >> 16) & 1);
  return (unsigned short)(r >> 16);
}

// ---- Wtb[i][c][k] = bf16(W[i*256+k][c]) ----
__global__ __launch_bounds__(256) void k_cvt_w(const float* __restrict__ W,
                                               unsigned short* __restrict__ Wtb) {
  const int i = blockIdx.y;
  const int k0 = blockIdx.x * 32;
  const int t = threadIdx.x;
  __shared__ float tile[32][129];
  #pragma unroll
  for (int j = 0; j < 16; ++j) {
    int idx = t + j * 256;
    int r = idx >> 7, c = idx & 127;
    tile[r][c] = W[(size_t)(i * IN_F + k0 + r) * OUT_F + c];
  }
  __syncthreads();
  const int c = t >> 1, half = t & 1;
  unsigned short* dst = Wtb + ((size_t)i * OUT_F + c) * IN_F + k0 + half * 16;
  #pragma unroll
  for (int g = 0; g < 4; ++g) {
    ushort4 v;
    v.x = f2bf(tile[half * 16 + g * 4 + 0][c]);
    v.y = f2bf(tile[half * 16 + g * 4 + 1][c]);
    v.z = f2bf(tile[half * 16 + g * 4 + 2][c]);
    v.w = f2bf(tile[half * 16 + g * 4 + 3][c]);
    *(ushort4*)(dst + g * 4) = v;
  }
}

// ---- K1 mega: Whnew_i = h@W_i (MFMA) -> Wh1/Wh2, ew2 (exp), gmax (atomicMax),
// Vopt fragment-order bf16 tiles, Whnew2 (i==2 only). grid (128,3), block 256. ----
__global__ __launch_bounds__(256) void k_front(const float* __restrict__ h,
                                               const unsigned short* __restrict__ Wtb,
                                               const float* __restrict__ a,
                                               float* __restrict__ Whnew2,
                                               unsigned short* __restrict__ Vopt,
                                               float* __restrict__ Wh1,
                                               float* __restrict__ Wh2,
                                               unsigned short* __restrict__ ew2pb,
                                               unsigned short* __restrict__ ew2mb,
                                               float* __restrict__ gmax2) {
  const int i = blockIdx.y;
  const int r0 = blockIdx.x * 32;
  const int t = threadIdx.x;
  const int lane = t & 63, wid = t >> 6;
  const int m = wid & 1, nh = wid >> 1, nbase = nh * 64;
  const int ln = lane & 15, lk = lane >> 4;

  __shared__ float a1s[128], a2s[128];
  __shared__ float red1[2][32], red2[2][32];
  __shared__ float ewsp[32], ewsm[32];
  __shared__ unsigned short T[2][32][130];

  if (t < 128) {
    a1s[t] = a[(size_t)2 * i * OUT_F + t];
    a2s[t] = a[(size_t)(2 * i + 1) * OUT_F + t];
  }
  __syncthreads();

  const float* ap = h + (size_t)(r0 + m * 16 + ln) * IN_F + lk * 8;
  const unsigned short* bp = Wtb + ((size_t)i * OUT_F + nbase + ln) * IN_F + lk * 8;

  f32x4 z4 = {0.f, 0.f, 0.f, 0.f};
  f32x4 acc[4] = {z4, z4, z4, z4};
  #pragma unroll
  for (int ks = 0; ks < 8; ++ks) {
    float4 h0 = *(const float4*)(ap + ks * 32);
    float4 h1 = *(const float4*)(ap + ks * 32 + 4);
    union { unsigned short u[8]; bf16x8 v; } av;
    av.u[0] = f2bf(h0.x); av.u[1] = f2bf(h0.y); av.u[2] = f2bf(h0.z); av.u[3] = f2bf(h0.w);
    av.u[4] = f2bf(h1.x); av.u[5] = f2bf(h1.y); av.u[6] = f2bf(h1.z); av.u[7] = f2bf(h1.w);
    acc[0] = __builtin_amdgcn_mfma_f32_16x16x32_bf16(av.v, *(const bf16x8*)(bp + 0 * 16 * IN_F + ks * 32), acc[0], 0, 0, 0);
    acc[1] = __builtin_amdgcn_mfma_f32_16x16x32_bf16(av.v, *(const bf16x8*)(bp + 1 * 16 * IN_F + ks * 32), acc[1], 0, 0, 0);
    acc[2] = __builtin_amdgcn_mfma_f32_16x16x32_bf16(av.v, *(const bf16x8*)(bp + 2 * 16 * IN_F + ks * 32), acc[2], 0, 0, 0);
    acc[3] = __builtin_amdgcn_mfma_f32_16x16x32_bf16(av.v, *(const bf16x8*)(bp + 3 * 16 * IN_F + ks * 32), acc[3], 0, 0, 0);
  }

  float d1[4] = {0.f, 0.f, 0.f, 0.f}, d2[4] = {0.f, 0.f, 0.f, 0.f};
  #pragma unroll
  for (int f = 0; f < 4; ++f) {
    const int col = nbase + f * 16 + ln;
    const float va1 = a1s[col], va2 = a2s[col];
    #pragma unroll
    for (int q = 0; q < 4; ++q) {
      const float v = acc[f][q];
      d1[q] += v * va1;
      d2[q] += v * va2;
    }
  }
  #pragma unroll
  for (int msk = 1; msk < 16; msk <<= 1) {
    #pragma unroll
    for (int q = 0; q < 4; ++q) {
      d1[q] += __shfl_xor(d1[q], msk, 64);
      d2[q] += __shfl_xor(d2[q], msk, 64);
    }
  }
  if (ln == 0) {
    #pragma unroll
    for (int q = 0; q < 4; ++q) {
      red1[nh][m * 16 + lk * 4 + q] = d1[q];
      red2[nh][m * 16 + lk * 4 + q] = d2[q];
    }
  }
  if (i == 2) {
    #pragma unroll
    for (int f = 0; f < 4; ++f) {
      const int col = nbase + f * 16 + ln;
      #pragma unroll
      for (int q = 0; q < 4; ++q)
        Whnew2[(size_t)(r0 + m * 16 + lk * 4 + q) * OUT_F + col] = acc[f][q];
    }
  }
  __syncthreads();

  if (t < 32) {
    const float w1 = red1[0][t] + red1[1][t];
    const float w2 = red2[0][t] + red2[1][t];
    Wh1[(size_t)i * NN + r0 + t] = w1;
    Wh2[(size_t)i * NN + r0 + t] = w2;
    const float ep = __expf(w2), em = __expf(ALPHA * w2);
    ewsp[t] = ep; ewsm[t] = em;
    ew2pb[(size_t)i * NN + r0 + t] = f2bf(ep);
    ew2mb[(size_t)i * NN + r0 + t] = f2bf(em);
    float mv = w2;
    #pragma unroll
    for (int o = 16; o > 0; o >>= 1) mv = fmaxf(mv, __shfl_down(mv, o, 32));
    if (t == 0 && mv > 0.f)
      atomicMax((int*)gmax2 + i, __float_as_int(mv));
  }
  __syncthreads();

  // scatter e~*v products into transpose tile (c-major -> n-major)
  #pragma unroll
  for (int f = 0; f < 4; ++f) {
    const int n = nbase + f * 16 + ln;
    #pragma unroll
    for (int q = 0; q < 4; ++q) {
      const int c = m * 16 + lk * 4 + q;
      const float v = acc[f][q];
      T[0][c][n] = f2bf(ewsp[c] * v);
      T[1][c][n] = f2bf(ewsm[c] * v);
    }
  }
  __syncthreads();

  // coalesced fragment-order write: Vopt[(i*2+s)*256 + kslab][n][cl]
  const int n = t & 127, ks = t >> 7;
  const int kslab = (r0 >> 4) + ks;
  #pragma unroll
  for (int s = 0; s < 2; ++s) {
    union { unsigned short u[16]; uint4 q[2]; } o;
    #pragma unroll
    for (int j = 0; j < 16; ++j) o.u[j] = T[s][ks * 16 + j][n];
    unsigned short* dst = Vopt + (((size_t)(i * 2 + s) * 256 + kslab) * 128 + n) * 16;
    *(uint4*)(dst) = o.q[0];
    *(uint4*)(dst + 8) = o.q[1];
  }
}

// ---- K_heavy: 128 rows x 512 cols per block, 8 waves. Phase 1: lane-packed
// mask stream -> nibble bits in LDS. Phase 2: V+/V- double-buffered through LDS
// (reg-staged, issue-early/write-late), all 8 waves share staged lines; 5 MFMAs
// per kslab from LDS only. grid (32,3,8) XCD-swizzled, 2 blocks/CU. ----
__global__ __launch_bounds__(512, 4) void k_heavy(const unsigned short* __restrict__ Vopt,
                                                  const int* __restrict__ mask,
                                                  const float* __restrict__ Wh1,
                                                  const float* __restrict__ Wh2,
                                                  const unsigned short* __restrict__ ew2pb,
                                                  const unsigned short* __restrict__ ew2mb,
                                                  const float* __restrict__ gmax2,
                                                  float* __restrict__ Upart,
                                                  float* __restrict__ SPp,
                                                  float* __restrict__ SMp) {
  // bijective XCD swizzle over 768 blocks: 96 consecutive works per XCD
  const unsigned int lid = blockIdx.x + 32u * (blockIdx.y + 3u * blockIdx.z);
  const unsigned int swz = (lid & 7u) * 96u + (lid >> 3);
  const int bx = swz & 31;          // row tile
  const int w = swz >> 5;           // 0..23
  const int i = w % 3;
  const int z = w / 3;

  const int r0 = bx * ROWS;
  const int cb = z * WCOLS;
  const int t = threadIdx.x;        // 0..511
  const int lane = t & 63, wid = t >> 6;   // 8 waves
  const int g = wid & 3, nh = wid >> 2;
  const int l31 = lane & 31, kh = lane >> 5;
  const int n0 = nh * 64 + l31, n1 = n0 + 32;

  __shared__ unsigned char bits8[ROWS][132];        // nibble-packed bp|bm<<4, padded stride
  __shared__ unsigned short Vl[2][2][2][2048];      // [buf][sign][slab][n*16+c] 32 KB
  __shared__ unsigned short ews[2][WCOLS];          // e^{w2}, e^{a w2} bf16

  // staging roles (4 waves P, 4 waves M; identity copy of 2-slab sign blocks)
  const int sg_st = wid >> 2;       // 0: P, 1: M  (wid 0-3 P, 4-7 M)
  const int q4 = wid & 3;
  const unsigned short* myWin = Vopt + ((size_t)(i * 2 + sg_st) * 256 + (cb >> 4)) * 2048;
  uint4 stg0, stg1;

  // issue chunk-0 loads first (latency overlaps phase 1)
  {
    const unsigned short* src = myWin + q4 * 1024 + lane * 8;
    stg0 = *(const uint4*)(src);
    stg1 = *(const uint4*)(src + 512);
  }

  // stage e^{w2} tables
  if (t < WCOLS) {
    ews[0][t] = ew2pb[(size_t)i * NN + cb + t];
    ews[1][t] = ew2mb[(size_t)i * NN + cb + t];
  }

  // ---- Phase 1: mask -> bits8 (fully lane-packed loads, per-lane u8 writes)
  {
    const float* w2base = Wh2 + (size_t)i * NN + cb;
    float4 w2a = *(const float4*)(w2base + lane * 4);
    float4 w2b = *(const float4*)(w2base + 256 + lane * 4);
    const int* mbase = mask + ((size_t)i * NN + r0) * NN + cb;
    for (int p = 0; p < 16; ++p) {
      const int r = p * 8 + wid;
      const float w1 = Wh1[(size_t)i * NN + r0 + r];
      const int* mp = mbase + (size_t)r * NN;
      int4 ma = *(const int4*)(mp + lane * 4);
      int4 mb = *(const int4*)(mp + 256 + lane * 4);
      unsigned int b0 = 0, b1 = 0;
      if (ma.x > 0) { if (w1 + w2a.x > 0.f) b0 |= 1u;  else b0 |= 16u; }
      if (ma.y > 0) { if (w1 + w2a.y > 0.f) b0 |= 2u;  else b0 |= 32u; }
      if (ma.z > 0) { if (w1 + w2a.z > 0.f) b0 |= 4u;  else b0 |= 64u; }
      if (ma.w > 0) { if (w1 + w2a.w > 0.f) b0 |= 8u;  else b0 |= 128u; }
      if (mb.x > 0) { if (w1 + w2b.x > 0.f) b1 |= 1u;  else b1 |= 16u; }
      if (mb.y > 0) { if (w1 + w2b.y > 0.f) b1 |= 2u;  else b1 |= 32u; }
      if (mb.z > 0) { if (w1 + w2b.z > 0.f) b1 |= 4u;  else b1 |= 64u; }
      if (mb.w > 0) { if (w1 + w2b.w > 0.f) b1 |= 8u;  else b1 |= 128u; }
      bits8[r][lane] = (unsigned char)b0;
      bits8[r][64 + lane] = (unsigned char)b1;
    }
  }

  __syncthreads();                  // bits + ews visible (nobody has read Vl yet)
  {                                 // write chunk 0
    unsigned short* dst = &Vl[0][sg_st][0][0] + q4 * 1024 + lane * 8;
    *(uint4*)dst = stg0;
    *(uint4*)(dst + 512) = stg1;
  }
  __syncthreads();                  // Vl[0] ready

  const int arow = g * 32 + l31;
  f32x16 accP0 = {}, accP1 = {}, accM0 = {}, accM1 = {}, accS = {};

  for (int c = 0; c < 16; ++c) {
    if (c < 15) {                   // T14: issue next chunk early
      const unsigned short* src = myWin + (size_t)(c + 1) * 4096 + q4 * 1024 + lane * 8;
      stg0 = *(const uint4*)(src);
      stg1 = *(const uint4*)(src + 512);
    }
    const int buf = c & 1;
    #pragma unroll
    for (int sc = 0; sc < 2; ++sc) {
      const int s = 2 * c + sc;
      const unsigned int w32 = *(const unsigned int*)&bits8[arow][s * 4];
      const unsigned int hw = (w32 >> (kh * 16)) & 0xFFFFu;
      union { unsigned int u[4]; bf16x8 v; } aP, aM;
      #pragma unroll
      for (int e = 0; e < 4; ++e) {
        const int base = 2 * e + ((e >> 1) << 2);   // 0,2,8,10
        aP.u[e] = ((hw >> base) & 1u) * 0x3F80u + ((hw >> (base + 1)) & 1u) * 0x3F800000u;
        aM.u[e] = ((hw >> (base + 4)) & 1u) * 0x3F80u + ((hw >> (base + 5)) & 1u) * 0x3F800000u;
      }
      bf16x8 bP0 = *(const bf16x8*)&Vl[buf][0][sc][n0 * 16 + kh * 8];
      bf16x8 bP1 = *(const bf16x8*)&Vl[buf][0][sc][n1 * 16 + kh * 8];
      bf16x8 bM0 = *(const bf16x8*)&Vl[buf][1][sc][n0 * 16 + kh * 8];
      bf16x8 bM1 = *(const bf16x8*)&Vl[buf][1][sc][n1 * 16 + kh * 8];
      bf16x8 eF  = *(const bf16x8*)&ews[nh][s * 16 + kh * 8];
      accP0 = __builtin_amdgcn_mfma_f32_32x32x16_bf16(aP.v, bP0, accP0, 0, 0, 0);
      accP1 = __builtin_amdgcn_mfma_f32_32x32x16_bf16(aP.v, bP1, accP1, 0, 0, 0);
      accM0 = __builtin_amdgcn_mfma_f32_32x32x16_bf16(aM.v, bM0, accM0, 0, 0, 0);
      accM1 = __builtin_amdgcn_mfma_f32_32x32x16_bf16(aM.v, bM1, accM1, 0, 0, 0);
      accS  = __builtin_amdgcn_mfma_f32_32x32x16_bf16(nh == 0 ? aP.v : aM.v, eF, accS, 0, 0, 0);
    }
    if (c < 15) {
      __syncthreads();              // all waves done reading Vl[buf^1]
      unsigned short* dst = &Vl[buf ^ 1][sg_st][0][0] + q4 * 1024 + lane * 8;
      *(uint4*)dst = stg0;
      *(uint4*)(dst + 512) = stg1;
      __syncthreads();              // next chunk ready
    }
  }

  const float gi = gmax2[i];
  const int rbase = r0 + g * 32;
  #pragma unroll
  for (int q = 0; q < 16; ++q) {
    const int crow = (q & 3) + 8 * (q >> 2) + 4 * kh;
    const int r = rbase + crow;
    const float rw1 = Wh1[(size_t)i * NN + r];
    const float e0 = rw1 + gi;
    const float mx = (e0 > 0.f) ? e0 : ALPHA * e0;
    const float fp = __expf(rw1 - mx);
    const float fm = __expf(ALPHA * rw1 - mx);
    float* urow = Upart + ((size_t)(z * 3 + i) * NN + r) * OUT_F;
    urow[n0] = fp * accP0[q] + fm * accM0[q];
    urow[n1] = fp * accP1[q] + fm * accM1[q];
  }
  if (l31 == 0) {
    #pragma unroll
    for (int q = 0; q < 16; ++q) {
      const int r = rbase + (q & 3) + 8 * (q >> 2) + 4 * kh;
      if (nh == 0) SPp[(size_t)(z * 3 + i) * NN + r] = accS[q];
      else         SMp[(size_t)(z * 3 + i) * NN + r] = accS[q];
    }
  }
}

// ---- final: out = elu( sum_i coef_i*(Σz Up)/(fp ΣSP + fm ΣSM) + 0.125*Whnew2 ) ----
__global__ __launch_bounds__(256) void k_final(const float* __restrict__ Upart,
                                               const float* __restrict__ SPp,
                                               const float* __restrict__ SMp,
                                               const float* __restrict__ Wh1,
                                               const float* __restrict__ gmax2,
                                               const float* __restrict__ Whnew2,
                                               float* __restrict__ out) {
  int idx = blockIdx.x * 256 + threadIdx.x;
  int r = idx >> 7;
  float v = 0.125f * Whnew2[idx];
  #pragma unroll
  for (int i = 0; i < 3; ++i) {
    const float coef = (i == 0) ? 0.5f : (i == 1) ? 0.25f : 0.125f;
    const float w1 = Wh1[(size_t)i * NN + r];
    const float gi = gmax2[i];
    const float e0 = w1 + gi;
    const float mx = (e0 > 0.f) ? e0 : ALPHA * e0;
    const float fp = __expf(w1 - mx);
    const float fm = __expf(ALPHA * w1 - mx);
    float u = 0.f, sp = 0.f, sm = 0.f;
    #pragma unroll
    for (int zz = 0; zz < 8; ++zz) {
      u  += Upart[((size_t)(zz * 3 + i) * NN) * OUT_F + idx];
      sp += SPp[(size_t)(zz * 3 + i) * NN + r];
      sm += SMp[(size_t)(zz * 3 + i) * NN + r];
    }
    const float S = fp * sp + fm * sm;
    v += coef * u / S;
  }
  out[idx] = (v > 0.f) ? v : (__expf(v) - 1.0f);
}

extern "C" void kernel_launch(void* const* d_in, const int* in_sizes, int n_in,
                              void* d_out, int out_size, void* d_ws, size_t ws_size,
                              hipStream_t stream) {
  const float* h    = (const float*)d_in[0];
  const int*   mask = (const int*)d_in[1];
  const float* W    = (const float*)d_in[2];
  const float* a    = (const float*)d_in[3];
  float* out = (float*)d_out;

  float* Whnew2 = (float*)d_ws;                        // NN*128
  float* Wh1    = Whnew2 + (size_t)NN * OUT_F;         // 3*NN
  float* Wh2    = Wh1 + 3 * NN;                        // 3*NN
  float* gmax2  = Wh2 + 3 * NN;                        // 4
  float* Upart  = gmax2 + 4;                           // 8*3*NN*128
  float* SPp    = Upart + (size_t)8 * 3 * NN * OUT_F;  // 8*3*NN
  float* SMp    = SPp + 8 * 3 * NN;                    // 8*3*NN
  unsigned short* Wtb   = (unsigned short*)(SMp + 8 * 3 * NN);   // 3*128*256
  unsigned short* Vopt  = Wtb + (size_t)3 * OUT_F * IN_F;        // 3*2*256*128*16
  unsigned short* ew2pb = Vopt + (size_t)3 * 2 * 256 * 128 * 16; // 3*NN
  unsigned short* ew2mb = ew2pb + 3 * NN;                        // 3*NN

  hipMemsetAsync(gmax2, 0, 4 * sizeof(float), stream);  // 0 seeds atomicMax upper-bound logic
  k_cvt_w<<<dim3(8, 3), 256, 0, stream>>>(W, Wtb);
  k_front<<<dim3(128, 3), 256, 0, stream>>>(h, Wtb, a, Whnew2, Vopt, Wh1, Wh2, ew2pb, ew2mb, gmax2);
  k_heavy<<<dim3(32, 3, 8), 512, 0, stream>>>(Vopt, mask, Wh1, Wh2, ew2pb, ew2mb, gmax2, Upart, SPp, SMp);
  k_final<<<(NN * OUT_F) / 256, 256, 0, stream>>>(Upart, SPp, SMp, Wh1, gmax2, Whnew2, out);
}